// Round 3
// baseline (1046.363 us; speedup 1.0000x reference)
//
#include <hip/hip_runtime.h>
#include <math.h>

// Problem constants
#define NNODE 256
#define FF    255      // feature dim
#define F2    510      // 2*F
#define EE    65536
#define HH    2048
#define OUTN  32640

typedef float vf4 __attribute__((ext_vector_type(4)));

// Workspace layout (float offsets)
#define OFF_W1P 0                    // 3 * 512*512   (W1 padded, b1 in col 510, unit row 510)
#define OFF_W2P 786432               // 3 * 256*512   (W2 padded, b2 in col 510, unit row 255)
#define OFF_W3P 1179648              // 3 * 256*256   (W3 padded, b3 in col 255)
#define OFF_T   1376256              // 3 * 256*512   T = W2p @ W1p
#define OFF_K   1769472              // (K no longer materialized) -> ping-pong U2/V2 live here
#define OFF_U2  OFF_K                // 256*256
#define OFF_V2  (OFF_K + 65536)      // 256*256
#define OFF_KDT 2162688              // 3 * 256*256   (Ka-Kb)^T, [k][o]
#define OFF_KBT 2359296              // 3 * 256*256   Kb^T, [k][o]
#define OFF_BEFF 2555904             // 3 * 256
#define OFF_GP  2556672              // 4 * 256*256   g0..g3 (padded col 255 = 0)
#define OFF_U   2818816              // 256*256
#define OFF_V   2884352              // 256*256  (must be right after U)
#define OFF_G3C 2949888              // 65280 compact g3.ravel()
#define OFF_Y   3015168              // 2048
#define OFF_MASK_BYTES (3017216L*4)  // 256*4 u64 = 8192 bytes

struct PrepArgs {
    const float* x;
    const int*   ei;
    const float* W1[3]; const float* b1[3];
    const float* W2[3]; const float* b2[3];
    const float* W3[3]; const float* b3[3];
};

// Pads weights with affine augmentation, pads x, builds adjacency bitmask.
__global__ __launch_bounds__(256) void prep_kernel(PrepArgs a, float* __restrict__ ws,
                                                   unsigned long long* __restrict__ mask) {
    int b = blockIdx.x, t = threadIdx.x;
    if (b < 1536) {                      // W1p: [512][512] per layer
        int l = b >> 9, r = b & 511;
        const float* W1 = a.W1[l]; const float* b1 = a.b1[l];
        float* dst = ws + OFF_W1P + l * (512 * 512) + r * 512;
        for (int c = t; c < 512; c += 256) {
            float v = 0.f;
            if (r < F2 && c < F2)      v = W1[r * F2 + c];
            else if (c == F2)          v = (r < F2) ? b1[r] : ((r == F2) ? 1.f : 0.f);
            dst[c] = v;
        }
    } else if (b < 2304) {               // W2p: [256][512] per layer
        int bb = b - 1536; int l = bb >> 8, r = bb & 255;
        const float* W2 = a.W2[l]; const float* b2 = a.b2[l];
        float* dst = ws + OFF_W2P + l * (256 * 512) + r * 512;
        for (int c = t; c < 512; c += 256) {
            float v = 0.f;
            if (r < FF && c < F2)      v = W2[r * F2 + c];
            else if (c == F2)          v = (r < FF) ? b2[r] : 1.f;   // row 255 = unit
            dst[c] = v;
        }
    } else if (b < 3072) {               // W3p: [256][256] per layer
        int bb = b - 2304; int l = bb >> 8, r = bb & 255;
        float* dst = ws + OFF_W3P + l * (256 * 256) + r * 256;
        float v = 0.f;
        if (r < FF) {
            if (t < FF)       v = a.W3[l][r * FF + t];
            else if (t == FF) v = a.b3[l][r];
        }
        dst[t] = v;
    } else if (b < 3328) {               // gp0: padded x
        int r = b - 3072;
        float* dst = ws + OFF_GP + r * 256;
        dst[t] = (t < FF) ? a.x[r * FF + t] : 0.f;
    } else {                             // adjacency bitmask from edge_index
        int e = (b - 3328) * 256 + t;
        int s = a.ei[e];                 // src
        int d = a.ei[EE + e];            // dst
        atomicOr(&mask[d * 4 + (s >> 6)], 1ull << (s & 63));
    }
}

// Row-parallel GEMM: C[256 x NCOL] = A[256 x KDIM] @ B[KDIM x NCOL].
// 4 rows per block; A loads are wave-uniform (scalarized), B streamed coalesced.
template <int KDIM, int NCOL>
__global__ __launch_bounds__(256) void rowgemm(const float* __restrict__ A, long sA,
                                               const float* __restrict__ B, long sB,
                                               float* __restrict__ C, long sC) {
    A += (long)blockIdx.z * sA + (long)blockIdx.x * 4 * KDIM;
    B += (long)blockIdx.z * sB;
    C += (long)blockIdx.z * sC + (long)blockIdx.x * 4 * NCOL;
    int t = threadIdx.x;
    if (NCOL == 512) {
        const float2* B2 = (const float2*)B;
        float2 a0 = {0.f, 0.f}, a1 = {0.f, 0.f}, a2 = {0.f, 0.f}, a3 = {0.f, 0.f};
        #pragma unroll 4
        for (int k = 0; k < KDIM; k++) {
            float2 bv = B2[k * (NCOL / 2) + t];
            float w0 = A[0 * KDIM + k], w1 = A[1 * KDIM + k];
            float w2 = A[2 * KDIM + k], w3 = A[3 * KDIM + k];
            a0.x += w0 * bv.x; a0.y += w0 * bv.y;
            a1.x += w1 * bv.x; a1.y += w1 * bv.y;
            a2.x += w2 * bv.x; a2.y += w2 * bv.y;
            a3.x += w3 * bv.x; a3.y += w3 * bv.y;
        }
        float2* C2 = (float2*)C;
        C2[0 * (NCOL / 2) + t] = a0;
        C2[1 * (NCOL / 2) + t] = a1;
        C2[2 * (NCOL / 2) + t] = a2;
        C2[3 * (NCOL / 2) + t] = a3;
    } else {
        float a0 = 0.f, a1 = 0.f, a2 = 0.f, a3 = 0.f;
        #pragma unroll 4
        for (int k = 0; k < KDIM; k++) {
            float bv = B[k * NCOL + t];
            a0 += A[0 * KDIM + k] * bv;
            a1 += A[1 * KDIM + k] * bv;
            a2 += A[2 * KDIM + k] * bv;
            a3 += A[3 * KDIM + k] * bv;
        }
        C[0 * NCOL + t] = a0;
        C[1 * NCOL + t] = a1;
        C[2 * NCOL + t] = a2;
        C[3 * NCOL + t] = a3;
    }
}

// K-fold GEMM with fused split: computes 4 rows of K = W3p @ T per block (z = layer),
// stages the 4x512 tile in LDS, then writes KdT[k][o] = K[o][k]-K[o][255+k],
// KbT[k][o] = K[o][255+k], beff[o] = K[o][510] directly. K never hits global.
__global__ __launch_bounds__(256) void rowgemmK(float* __restrict__ ws) {
    int l = blockIdx.z, t = threadIdx.x, r0 = blockIdx.x * 4;
    const float*  A  = ws + OFF_W3P + l * 65536 + r0 * 256;
    const float2* B2 = (const float2*)(ws + OFF_T + l * 131072);
    float2 a0 = {0.f, 0.f}, a1 = {0.f, 0.f}, a2 = {0.f, 0.f}, a3 = {0.f, 0.f};
    #pragma unroll 4
    for (int k = 0; k < 256; k++) {
        float2 bv = B2[k * 256 + t];
        float w0 = A[0 * 256 + k], w1 = A[1 * 256 + k];
        float w2 = A[2 * 256 + k], w3 = A[3 * 256 + k];
        a0.x += w0 * bv.x; a0.y += w0 * bv.y;
        a1.x += w1 * bv.x; a1.y += w1 * bv.y;
        a2.x += w2 * bv.x; a2.y += w2 * bv.y;
        a3.x += w3 * bv.x; a3.y += w3 * bv.y;
    }
    __shared__ float Kt[4][512];
    Kt[0][2 * t] = a0.x; Kt[0][2 * t + 1] = a0.y;
    Kt[1][2 * t] = a1.x; Kt[1][2 * t + 1] = a1.y;
    Kt[2][2 * t] = a2.x; Kt[2][2 * t + 1] = a2.y;
    Kt[3][2 * t] = a3.x; Kt[3][2 * t + 1] = a3.y;
    __syncthreads();
    float* KdT = ws + OFF_KDT + l * 65536;
    float* KbT = ws + OFF_KBT + l * 65536;
    if (t < FF) {
        #pragma unroll
        for (int r = 0; r < 4; r++) {
            float k1 = Kt[r][t], k2 = Kt[r][FF + t];
            KdT[t * 256 + r0 + r] = k1 - k2;
            KbT[t * 256 + r0 + r] = k2;
        }
    } else if (t == FF) {
        #pragma unroll
        for (int r = 0; r < 4; r++) {
            KdT[FF * 256 + r0 + r] = 0.f;
            KbT[FF * 256 + r0 + r] = 0.f;
        }
    }
    if (t < 4) ws[OFF_BEFF + l * 256 + r0 + t] = Kt[t][F2];
}

// Fused: agg for 4 dst rows (masked max over V + epilogue) -> g rows in LDS+global,
// then the NEXT layer's GEMM for those rows: Uo = g @ Bd, Vo = g @ Bb.
// Uo/Vo MUST differ from U/V (other blocks still reading V) -> ping-pong buffers.
template <int HAS_RES>
__global__ __launch_bounds__(256) void agg_gemm(const float* __restrict__ U,
                                                const float* __restrict__ V,
                                                const float* __restrict__ beff,
                                                const float* __restrict__ gprev,
                                                float* __restrict__ gout,
                                                const unsigned long long* __restrict__ mask,
                                                const float* __restrict__ Bd,
                                                const float* __restrict__ Bb,
                                                float* __restrict__ Uo,
                                                float* __restrict__ Vo) {
    int r0 = blockIdx.x * 4, t = threadIdx.x;
    __shared__ float gs[4][256];
    __shared__ unsigned long long ms[4][4];
    if (t < 16) ms[t >> 2][t & 3] = mask[r0 * 4 + t];
    __syncthreads();
    float vm0 = -INFINITY, vm1 = -INFINITY, vm2 = -INFINITY, vm3 = -INFINITY;
    #pragma unroll
    for (int w = 0; w < 4; w++) {
        unsigned long long w0 = ms[0][w], w1 = ms[1][w], w2 = ms[2][w], w3 = ms[3][w];
        const float* Vp = V + w * 64 * 256 + t;
        #pragma unroll 8
        for (int j = 0; j < 64; j++) {
            float v = Vp[j * 256];
            vm0 = ((w0 >> j) & 1) ? fmaxf(vm0, v) : vm0;
            vm1 = ((w1 >> j) & 1) ? fmaxf(vm1, v) : vm1;
            vm2 = ((w2 >> j) & 1) ? fmaxf(vm2, v) : vm2;
            vm3 = ((w3 >> j) & 1) ? fmaxf(vm3, v) : vm3;
        }
    }
    float be = beff[t];
    float vms[4] = {vm0, vm1, vm2, vm3};
    #pragma unroll
    for (int i = 0; i < 4; i++) {
        bool any = (ms[i][0] | ms[i][1] | ms[i][2] | ms[i][3]) != 0ull;
        float val = any ? (U[(r0 + i) * 256 + t] + be + vms[i]) : 0.f;
        if (HAS_RES) val += gprev[(r0 + i) * 256 + t];
        float g = fmaxf(val, 0.f);
        gs[i][t] = g;
        gout[(r0 + i) * 256 + t] = g;
    }
    __syncthreads();
    float u0 = 0.f, u1 = 0.f, u2 = 0.f, u3 = 0.f;
    float v0 = 0.f, v1 = 0.f, v2 = 0.f, v3 = 0.f;
    #pragma unroll 4
    for (int k = 0; k < 256; k++) {
        float bd = Bd[k * 256 + t], bb = Bb[k * 256 + t];
        float g0 = gs[0][k], g1 = gs[1][k], g2 = gs[2][k], g3 = gs[3][k];
        u0 += g0 * bd; u1 += g1 * bd; u2 += g2 * bd; u3 += g3 * bd;
        v0 += g0 * bb; v1 += g1 * bb; v2 += g2 * bb; v3 += g3 * bb;
    }
    Uo[(r0 + 0) * 256 + t] = u0; Uo[(r0 + 1) * 256 + t] = u1;
    Uo[(r0 + 2) * 256 + t] = u2; Uo[(r0 + 3) * 256 + t] = u3;
    Vo[(r0 + 0) * 256 + t] = v0; Vo[(r0 + 1) * 256 + t] = v1;
    Vo[(r0 + 2) * 256 + t] = v2; Vo[(r0 + 3) * 256 + t] = v3;
}

// Final-layer agg (standalone): per-dst masked max + epilogue + g3c compaction.
__global__ __launch_bounds__(256) void agg_kernel(const float* __restrict__ U,
                                                  const float* __restrict__ V,
                                                  const float* __restrict__ beff,
                                                  const float* __restrict__ gprev,
                                                  float* __restrict__ gout,
                                                  float* __restrict__ g3c,
                                                  const unsigned long long* __restrict__ mask,
                                                  int has_res) {
    int i = blockIdx.x, f = threadIdx.x;
    __shared__ unsigned long long mw[4];
    if (f < 4) mw[f] = mask[i * 4 + f];
    __syncthreads();
    unsigned long long m0 = mw[0], m1 = mw[1], m2 = mw[2], m3 = mw[3];
    unsigned long long mr[4] = {m0, m1, m2, m3};
    float vm = -INFINITY;
    #pragma unroll
    for (int w = 0; w < 4; w++) {
        unsigned long long mword = mr[w];
        const float* Vp = V + w * 64 * 256 + f;
        #pragma unroll 8
        for (int j = 0; j < 64; j++) {
            float v = Vp[j * 256];
            vm = ((mword >> j) & 1) ? fmaxf(vm, v) : vm;
        }
    }
    bool any = (m0 | m1 | m2 | m3) != 0ull;
    float val = any ? (U[i * 256 + f] + beff[f] + vm) : 0.f;
    if (has_res) val += gprev[i * 256 + f];
    float g = fmaxf(val, 0.f);
    gout[i * 256 + f] = g;
    if (g3c && f < FF) g3c[i * FF + f] = g;
}

// y = relu(l4_W @ g3c + l4_b); 1 row/block x 2048 blocks (32 waves/CU TLP),
// nontemporal W stream (read-once, 534 MB >> L3).
__global__ __launch_bounds__(256) void l4_kernel(const float* __restrict__ W,
                                                 const float* __restrict__ bias,
                                                 const float* __restrict__ g3c,
                                                 float* __restrict__ y) {
    int row = blockIdx.x, t = threadIdx.x;
    const int K4 = 65280 / 4;   // 16320
    const vf4* Wp = (const vf4*)W + (long)row * K4;
    const vf4* G4 = (const vf4*)g3c;
    float a = 0.f;
    for (int v = t; v < K4; v += 256) {
        vf4 g = G4[v];
        vf4 w = __builtin_nontemporal_load(&Wp[v]);
        a += w.x * g.x + w.y * g.y + w.z * g.z + w.w * g.w;
    }
    #pragma unroll
    for (int off = 32; off; off >>= 1) a += __shfl_xor(a, off);
    __shared__ float red[4];
    int wv = t >> 6, ln = t & 63;
    if (ln == 0) red[wv] = a;
    __syncthreads();
    if (t == 0) y[row] = fmaxf(red[0] + red[1] + red[2] + red[3] + bias[row], 0.f);
}

// out = out_W @ y + out_b; one wave per row, nontemporal W stream.
__global__ __launch_bounds__(256) void out_kernel(const float* __restrict__ W,
                                                  const float* __restrict__ bias,
                                                  const float* __restrict__ y,
                                                  float* __restrict__ out) {
    int wv = threadIdx.x >> 6, ln = threadIdx.x & 63;
    int r = blockIdx.x * 4 + wv;
    const vf4* W4 = (const vf4*)(W + (long)r * HH);
    const vf4* Y4 = (const vf4*)y;
    float acc = 0.f;
    #pragma unroll
    for (int i = 0; i < 8; i++) {
        vf4 w  = __builtin_nontemporal_load(&W4[ln + 64 * i]);
        vf4 yy = Y4[ln + 64 * i];
        acc += w.x * yy.x + w.y * yy.y + w.z * yy.z + w.w * yy.w;
    }
    #pragma unroll
    for (int off = 32; off; off >>= 1) acc += __shfl_xor(acc, off);
    if (ln == 0) out[r] = acc + bias[r];
}

extern "C" void kernel_launch(void* const* d_in, const int* in_sizes, int n_in,
                              void* d_out, int out_size, void* d_ws, size_t ws_size,
                              hipStream_t stream) {
    float* ws = (float*)d_ws;
    unsigned long long* mask = (unsigned long long*)((char*)d_ws + OFF_MASK_BYTES);

    PrepArgs pa;
    pa.x  = (const float*)d_in[0];
    pa.ei = (const int*)d_in[1];
    for (int l = 0; l < 3; l++) {
        pa.W1[l] = (const float*)d_in[2 + l * 6 + 0];
        pa.b1[l] = (const float*)d_in[2 + l * 6 + 1];
        pa.W2[l] = (const float*)d_in[2 + l * 6 + 2];
        pa.b2[l] = (const float*)d_in[2 + l * 6 + 3];
        pa.W3[l] = (const float*)d_in[2 + l * 6 + 4];
        pa.b3[l] = (const float*)d_in[2 + l * 6 + 5];
    }
    const float* l4W  = (const float*)d_in[20];
    const float* l4b  = (const float*)d_in[21];
    const float* outW = (const float*)d_in[22];
    const float* outb = (const float*)d_in[23];

    (void)hipMemsetAsync(mask, 0, 8192, stream);
    prep_kernel<<<3584, 256, 0, stream>>>(pa, ws, mask);

    // T = W2p @ W1p  (per layer, batched over z)
    rowgemm<512, 512><<<dim3(64, 1, 3), 256, 0, stream>>>(
        ws + OFF_W2P, 131072, ws + OFF_W1P, 262144, ws + OFF_T, 131072);
    // K = W3p @ T fused with split -> KdT/KbT/beff
    rowgemmK<<<dim3(64, 1, 3), 256, 0, stream>>>(ws);

    // Layer 0 GEMM: U = g0 @ KdT0 (z=0), V = g0 @ KbT0 (z=1)
    rowgemm<256, 256><<<dim3(64, 1, 2), 256, 0, stream>>>(
        ws + OFF_GP, 0, ws + OFF_KDT, OFF_KBT - OFF_KDT, ws + OFF_U, 65536);

    // agg0 -> g1, then GEMM1 into ping-pong U2/V2
    agg_gemm<0><<<64, 256, 0, stream>>>(
        ws + OFF_U, ws + OFF_V, ws + OFF_BEFF, ws + OFF_GP, ws + OFF_GP + 65536, mask,
        ws + OFF_KDT + 65536, ws + OFF_KBT + 65536, ws + OFF_U2, ws + OFF_V2);
    // agg1 -> g2, then GEMM2 back into U/V
    agg_gemm<1><<<64, 256, 0, stream>>>(
        ws + OFF_U2, ws + OFF_V2, ws + OFF_BEFF + 256, ws + OFF_GP + 65536,
        ws + OFF_GP + 2 * 65536, mask,
        ws + OFF_KDT + 2 * 65536, ws + OFF_KBT + 2 * 65536, ws + OFF_U, ws + OFF_V);
    // agg2 -> g3 + compact g3c
    agg_kernel<<<256, 256, 0, stream>>>(
        ws + OFF_U, ws + OFF_V, ws + OFF_BEFF + 512, ws + OFF_GP + 2 * 65536,
        ws + OFF_GP + 3 * 65536, ws + OFF_G3C, mask, 1);

    l4_kernel<<<2048, 256, 0, stream>>>(l4W, l4b, ws + OFF_G3C, ws + OFF_Y);
    out_kernel<<<8160, 256, 0, stream>>>(outW, outb, ws + OFF_Y, (float*)d_out);
}